// Round 6
// baseline (235.038 us; speedup 1.0000x reference)
//
#include <hip/hip_runtime.h>

#define M_MEANS 256

typedef float f32x4 __attribute__((ext_vector_type(4)));

// Spread row ownership for a compact sliding write window:
//   W = total waves (2048). Wave w owns rows {w + W*k, k=0..511}, processed in
//   8 batches of 64 (lane l <-> row w + W*(64b+l)).
//   Store loop iteration j: ALL waves write row w + W*(64b+j) -> the chip's
//   active store window is one contiguous 2 MB stripe sliding through the
//   output (fill-kernel-like), instead of 8192 disjoint 64 KiB streams.
//   R4's software pipeline kept: batch b's store loop fuses batch b+1's argmin.
__global__ __launch_bounds__(256) void TemperatureModel_81767587381683_kernel(
    const float* __restrict__ target,
    const float* __restrict__ means,
    float* __restrict__ out,
    int N)
{
    __shared__ __align__(16) float sMeans[M_MEANS];

    const int tid  = threadIdx.x;
    const int lane = tid & 63;
    const int wave = tid >> 6;
    const int cbase = 4 * lane;

    sMeans[tid] = means[tid];
    __syncthreads();  // only barrier: means staging

    const int W = gridDim.x * 4;          // total waves (2048)
    const int w = blockIdx.x * 4 + wave;
    const int nBatches = N / (W * 64);    // 8

    // ---- Prologue: argmin for batch 0 (lane l -> row w + W*l) ----
    int bi; float bv;
    {
        const float t = target[w + W * lane];
        float bd0 = 3.4e38f, bd1 = 3.4e38f, bd2 = 3.4e38f, bd3 = 3.4e38f;
        int   bi0 = 0,       bi1 = 64,      bi2 = 128,     bi3 = 192;
        #pragma unroll 4
        for (int k = 0; k < 64; k += 4) {
            const f32x4 m0 = *reinterpret_cast<const f32x4*>(&sMeans[k]);
            const f32x4 m1 = *reinterpret_cast<const f32x4*>(&sMeans[64 + k]);
            const f32x4 m2 = *reinterpret_cast<const f32x4*>(&sMeans[128 + k]);
            const f32x4 m3 = *reinterpret_cast<const f32x4*>(&sMeans[192 + k]);
            #pragma unroll
            for (int j = 0; j < 4; ++j) {
                const float d0 = fabsf(m0[j] - t);
                const float d1 = fabsf(m1[j] - t);
                const float d2 = fabsf(m2[j] - t);
                const float d3 = fabsf(m3[j] - t);
                if (d0 < bd0) { bd0 = d0; bi0 = k + j; }
                if (d1 < bd1) { bd1 = d1; bi1 = 64 + k + j; }
                if (d2 < bd2) { bd2 = d2; bi2 = 128 + k + j; }
                if (d3 < bd3) { bd3 = d3; bi3 = 192 + k + j; }
            }
        }
        float bd = bd0; bi = bi0;
        if (bd1 < bd) { bd = bd1; bi = bi1; }
        if (bd2 < bd) { bd = bd2; bi = bi2; }
        if (bd3 < bd) { bd = bd3; bi = bi3; }
        bv = sMeans[bi];
    }

    // ---- Main loop: store batch b fused with argmin of batch b+1 ----
    const size_t rowStride = (size_t)W * M_MEANS;  // floats between successive j

    for (int b = 0; b < nBatches - 1; ++b) {
        // next batch's target: row w + W*(64*(b+1) + lane)
        const float tn = target[w + W * ((b + 1) * 64 + lane)];

        float nbd0 = 3.4e38f, nbd1 = 3.4e38f, nbd2 = 3.4e38f, nbd3 = 3.4e38f;
        int   nbi0 = 0,       nbi1 = 64,      nbi2 = 128,     nbi3 = 192;

        float* p = out + ((size_t)w + (size_t)W * (b * 64)) * M_MEANS + cbase;
        const int bvbits = __float_as_int(bv);

        #pragma unroll 4
        for (int j = 0; j < 64; ++j) {
            const int   sbi = __builtin_amdgcn_readlane(bi, j);
            const float sbv = __int_as_float(__builtin_amdgcn_readlane(bvbits, j));
            const int ee = sbi - cbase;
            f32x4 o;
            o.x = (ee == 0) ? sbv : 0.0f;
            o.y = (ee == 1) ? sbv : 0.0f;
            o.z = (ee == 2) ? sbv : 0.0f;
            o.w = (ee == 3) ? sbv : 0.0f;
            *reinterpret_cast<f32x4*>(p) = o;
            p += rowStride;

            const float d0 = fabsf(sMeans[j]       - tn);
            const float d1 = fabsf(sMeans[64 + j]  - tn);
            const float d2 = fabsf(sMeans[128 + j] - tn);
            const float d3 = fabsf(sMeans[192 + j] - tn);
            if (d0 < nbd0) { nbd0 = d0; nbi0 = j; }
            if (d1 < nbd1) { nbd1 = d1; nbi1 = 64 + j; }
            if (d2 < nbd2) { nbd2 = d2; nbi2 = 128 + j; }
            if (d3 < nbd3) { nbd3 = d3; nbi3 = 192 + j; }
        }

        float nbd = nbd0; int nbi = nbi0;
        if (nbd1 < nbd) { nbd = nbd1; nbi = nbi1; }
        if (nbd2 < nbd) { nbd = nbd2; nbi = nbi2; }
        if (nbd3 < nbd) { nbd = nbd3; nbi = nbi3; }
        bi = nbi;
        bv = sMeans[nbi];
    }

    // ---- Epilogue: store the final batch ----
    {
        const int b = nBatches - 1;
        float* p = out + ((size_t)w + (size_t)W * (b * 64)) * M_MEANS + cbase;
        const int bvbits = __float_as_int(bv);
        #pragma unroll 4
        for (int j = 0; j < 64; ++j) {
            const int   sbi = __builtin_amdgcn_readlane(bi, j);
            const float sbv = __int_as_float(__builtin_amdgcn_readlane(bvbits, j));
            const int ee = sbi - cbase;
            f32x4 o;
            o.x = (ee == 0) ? sbv : 0.0f;
            o.y = (ee == 1) ? sbv : 0.0f;
            o.z = (ee == 2) ? sbv : 0.0f;
            o.w = (ee == 3) ? sbv : 0.0f;
            *reinterpret_cast<f32x4*>(p) = o;
            p += rowStride;
        }
    }
}

extern "C" void kernel_launch(void* const* d_in, const int* in_sizes, int n_in,
                              void* d_out, int out_size, void* d_ws, size_t ws_size,
                              hipStream_t stream) {
    const float* target = (const float*)d_in[0];
    const float* means  = (const float*)d_in[1];
    float* out = (float*)d_out;
    const int N = in_sizes[0];  // 1,048,576

    // 512 blocks x 256 threads = 2048 waves; 512 rows/wave in 8 pipelined
    // batches; all waves co-resident (2 blocks/CU), sliding 2 MB write window.
    dim3 grid(512), block(256);
    hipLaunchKernelGGL(TemperatureModel_81767587381683_kernel, grid, block, 0, stream,
                       target, means, out, N);
}

// Round 7
// 209.282 us; speedup vs baseline: 1.1231x; 1.1231x over previous
//
#include <hip/hip_runtime.h>

#define M_MEANS 256

typedef float f32x4 __attribute__((ext_vector_type(4)));

// Wave w owns 256 CONTIGUOUS rows [256w, 256w+256) in 4 groups of 64
// (lane l <-> row 256w + 64b + l). All 4 per-lane target loads are issued at
// kernel start, so no fused iteration ever waits on a load stuck behind the
// store FIFO (vmcnt is in-order: a load used right after issue would force
// draining all outstanding stores). Store loop of group b is fused with the
// argmin of group b+1 (4 index-ordered chains -> exact first-index tie-break).
__global__ __launch_bounds__(256) void TemperatureModel_81767587381683_kernel(
    const float* __restrict__ target,
    const float* __restrict__ means,
    float* __restrict__ out,
    int N)
{
    __shared__ __align__(16) float sMeans[M_MEANS];

    const int tid  = threadIdx.x;
    const int lane = tid & 63;
    const int wave = tid >> 6;
    const int cbase = 4 * lane;

    sMeans[tid] = means[tid];
    __syncthreads();  // only barrier: means staging

    const int w = blockIdx.x * 4 + wave;     // 0..4095
    const int rowBase = w << 8;              // 256 rows per wave
    if (rowBase >= N) return;

    // Issue ALL target loads up-front (4 coalesced dword loads, 1 KiB/wave).
    // Uses are >2500 cycles later -> waitcnt never drains the store queue.
    const float t0 = target[rowBase + lane];
    const float t1 = target[rowBase + 64  + lane];
    const float t2 = target[rowBase + 128 + lane];
    const float t3 = target[rowBase + 192 + lane];

    // ---- Prologue: argmin for group 0 (t0) ----
    int bi; float bv;
    {
        float bd0 = 3.4e38f, bd1 = 3.4e38f, bd2 = 3.4e38f, bd3 = 3.4e38f;
        int   bi0 = 0,       bi1 = 64,      bi2 = 128,     bi3 = 192;
        #pragma unroll 4
        for (int k = 0; k < 64; k += 4) {
            const f32x4 m0 = *reinterpret_cast<const f32x4*>(&sMeans[k]);
            const f32x4 m1 = *reinterpret_cast<const f32x4*>(&sMeans[64 + k]);
            const f32x4 m2 = *reinterpret_cast<const f32x4*>(&sMeans[128 + k]);
            const f32x4 m3 = *reinterpret_cast<const f32x4*>(&sMeans[192 + k]);
            #pragma unroll
            for (int j = 0; j < 4; ++j) {
                const float d0 = fabsf(m0[j] - t0);
                const float d1 = fabsf(m1[j] - t0);
                const float d2 = fabsf(m2[j] - t0);
                const float d3 = fabsf(m3[j] - t0);
                if (d0 < bd0) { bd0 = d0; bi0 = k + j; }
                if (d1 < bd1) { bd1 = d1; bi1 = 64 + k + j; }
                if (d2 < bd2) { bd2 = d2; bi2 = 128 + k + j; }
                if (d3 < bd3) { bd3 = d3; bi3 = 192 + k + j; }
            }
        }
        float bd = bd0; bi = bi0;
        if (bd1 < bd) { bd = bd1; bi = bi1; }
        if (bd2 < bd) { bd = bd2; bi = bi2; }
        if (bd3 < bd) { bd = bd3; bi = bi3; }
        bv = sMeans[bi];
    }

    float* const base0 = out + (size_t)rowBase * M_MEANS + cbase;

    // Store group B with current (bi,bv); fuse argmin of next group's TN.
#define FUSED(B, TN)                                                          \
    {                                                                         \
        float nbd0 = 3.4e38f, nbd1 = 3.4e38f, nbd2 = 3.4e38f, nbd3 = 3.4e38f; \
        int   nbi0 = 0, nbi1 = 64, nbi2 = 128, nbi3 = 192;                    \
        float* p = base0 + (size_t)(B) * 64 * M_MEANS;                        \
        const int bvbits = __float_as_int(bv);                                \
        _Pragma("unroll 4")                                                   \
        for (int j = 0; j < 64; ++j) {                                        \
            const int   sbi = __builtin_amdgcn_readlane(bi, j);               \
            const float sbv = __int_as_float(__builtin_amdgcn_readlane(bvbits, j)); \
            const int ee = sbi - cbase;                                       \
            f32x4 o;                                                          \
            o.x = (ee == 0) ? sbv : 0.0f;                                     \
            o.y = (ee == 1) ? sbv : 0.0f;                                     \
            o.z = (ee == 2) ? sbv : 0.0f;                                     \
            o.w = (ee == 3) ? sbv : 0.0f;                                     \
            *reinterpret_cast<f32x4*>(p + (size_t)j * M_MEANS) = o;           \
            const float d0 = fabsf(sMeans[j]       - (TN));                   \
            const float d1 = fabsf(sMeans[64 + j]  - (TN));                   \
            const float d2 = fabsf(sMeans[128 + j] - (TN));                   \
            const float d3 = fabsf(sMeans[192 + j] - (TN));                   \
            if (d0 < nbd0) { nbd0 = d0; nbi0 = j; }                           \
            if (d1 < nbd1) { nbd1 = d1; nbi1 = 64 + j; }                      \
            if (d2 < nbd2) { nbd2 = d2; nbi2 = 128 + j; }                     \
            if (d3 < nbd3) { nbd3 = d3; nbi3 = 192 + j; }                     \
        }                                                                     \
        float nbd = nbd0; int nbi = nbi0;                                     \
        if (nbd1 < nbd) { nbd = nbd1; nbi = nbi1; }                           \
        if (nbd2 < nbd) { nbd = nbd2; nbi = nbi2; }                           \
        if (nbd3 < nbd) { nbd = nbd3; nbi = nbi3; }                           \
        bi = nbi; bv = sMeans[nbi];                                           \
    }

    FUSED(0, t1)
    FUSED(1, t2)
    FUSED(2, t3)
#undef FUSED

    // ---- Epilogue: store group 3 (no dead argmin work) ----
    {
        float* p = base0 + (size_t)3 * 64 * M_MEANS;
        const int bvbits = __float_as_int(bv);
        #pragma unroll 4
        for (int j = 0; j < 64; ++j) {
            const int   sbi = __builtin_amdgcn_readlane(bi, j);
            const float sbv = __int_as_float(__builtin_amdgcn_readlane(bvbits, j));
            const int ee = sbi - cbase;
            f32x4 o;
            o.x = (ee == 0) ? sbv : 0.0f;
            o.y = (ee == 1) ? sbv : 0.0f;
            o.z = (ee == 2) ? sbv : 0.0f;
            o.w = (ee == 3) ? sbv : 0.0f;
            *reinterpret_cast<f32x4*>(p + (size_t)j * M_MEANS) = o;
        }
    }
}

extern "C" void kernel_launch(void* const* d_in, const int* in_sizes, int n_in,
                              void* d_out, int out_size, void* d_ws, size_t ws_size,
                              hipStream_t stream) {
    const float* target = (const float*)d_in[0];
    const float* means  = (const float*)d_in[1];
    float* out = (float*)d_out;
    const int N = in_sizes[0];  // 1,048,576

    // 1024 blocks x 256 threads = 4096 waves (16/CU, 4/SIMD); wave w owns
    // 256 contiguous rows in 4 pipelined groups. Fill kernel hits 6.5 TB/s at
    // 11% occupancy -> 16 waves/CU is ample for write saturation; halving the
    // resident waves halves the all-compute prologue bubble.
    dim3 grid(1024), block(256);
    hipLaunchKernelGGL(TemperatureModel_81767587381683_kernel, grid, block, 0, stream,
                       target, means, out, N);
}

// Round 8
// 202.840 us; speedup vs baseline: 1.1587x; 1.0318x over previous
//
#include <hip/hip_runtime.h>

#define M_MEANS 256

typedef float f32x4 __attribute__((ext_vector_type(4)));

// Best-of-all-rounds recombination:
//  - 8192 waves (2048 blocks x 256): full 32 waves/CU residency — measured
//    best for write-queue depth (8192w:202, 4096w:209, 2048w:235 us).
//  - Wave w owns ONE contiguous 128-KiB region: rows [128w, 128w+128),
//    2 groups of 64 (no mid-wave 512-MB jump like R4's {w, w+8192} split).
//  - Both per-lane targets preloaded at kernel start: no load is ever
//    issued behind a full store FIFO (in-order vmcnt would force a drain).
//  - Group-0 store loop fused with group-1 argmin (4 index-ordered chains,
//    exact first-index tie-break); epilogue stores group 1.
__global__ __launch_bounds__(256) void TemperatureModel_81767587381683_kernel(
    const float* __restrict__ target,
    const float* __restrict__ means,
    float* __restrict__ out,
    int N)
{
    __shared__ __align__(16) float sMeans[M_MEANS];

    const int tid  = threadIdx.x;
    const int lane = tid & 63;
    const int wave = tid >> 6;
    const int cbase = 4 * lane;

    sMeans[tid] = means[tid];
    __syncthreads();  // only barrier: means staging

    const int w = blockIdx.x * 4 + wave;     // 0..8191
    const int rowBase = w << 7;              // 128 contiguous rows per wave
    if (rowBase >= N) return;

    // Preload both targets (2 coalesced dword loads; used >2500 cycles later).
    const float t0 = target[rowBase + lane];
    const float t1 = target[rowBase + 64 + lane];

    // ---- Prologue: argmin for group 0 (t0) ----
    int bi; float bv;
    {
        float bd0 = 3.4e38f, bd1 = 3.4e38f, bd2 = 3.4e38f, bd3 = 3.4e38f;
        int   bi0 = 0,       bi1 = 64,      bi2 = 128,     bi3 = 192;
        #pragma unroll 4
        for (int k = 0; k < 64; k += 4) {
            const f32x4 m0 = *reinterpret_cast<const f32x4*>(&sMeans[k]);
            const f32x4 m1 = *reinterpret_cast<const f32x4*>(&sMeans[64 + k]);
            const f32x4 m2 = *reinterpret_cast<const f32x4*>(&sMeans[128 + k]);
            const f32x4 m3 = *reinterpret_cast<const f32x4*>(&sMeans[192 + k]);
            #pragma unroll
            for (int j = 0; j < 4; ++j) {
                const float d0 = fabsf(m0[j] - t0);
                const float d1 = fabsf(m1[j] - t0);
                const float d2 = fabsf(m2[j] - t0);
                const float d3 = fabsf(m3[j] - t0);
                if (d0 < bd0) { bd0 = d0; bi0 = k + j; }
                if (d1 < bd1) { bd1 = d1; bi1 = 64 + k + j; }
                if (d2 < bd2) { bd2 = d2; bi2 = 128 + k + j; }
                if (d3 < bd3) { bd3 = d3; bi3 = 192 + k + j; }
            }
        }
        float bd = bd0; bi = bi0;
        if (bd1 < bd) { bd = bd1; bi = bi1; }
        if (bd2 < bd) { bd = bd2; bi = bi2; }
        if (bd3 < bd) { bd = bd3; bi = bi3; }
        bv = sMeans[bi];
    }

    float* const base0 = out + (size_t)rowBase * M_MEANS + cbase;

    // ---- Fused: store group 0, compute argmin of group 1 (t1) ----
    {
        float nbd0 = 3.4e38f, nbd1 = 3.4e38f, nbd2 = 3.4e38f, nbd3 = 3.4e38f;
        int   nbi0 = 0,       nbi1 = 64,      nbi2 = 128,     nbi3 = 192;
        const int bvbits = __float_as_int(bv);

        #pragma unroll 4
        for (int j = 0; j < 64; ++j) {
            const int   sbi = __builtin_amdgcn_readlane(bi, j);
            const float sbv = __int_as_float(__builtin_amdgcn_readlane(bvbits, j));
            const int ee = sbi - cbase;
            f32x4 o;
            o.x = (ee == 0) ? sbv : 0.0f;
            o.y = (ee == 1) ? sbv : 0.0f;
            o.z = (ee == 2) ? sbv : 0.0f;
            o.w = (ee == 3) ? sbv : 0.0f;
            *reinterpret_cast<f32x4*>(base0 + (size_t)j * M_MEANS) = o;

            const float d0 = fabsf(sMeans[j]       - t1);
            const float d1 = fabsf(sMeans[64 + j]  - t1);
            const float d2 = fabsf(sMeans[128 + j] - t1);
            const float d3 = fabsf(sMeans[192 + j] - t1);
            if (d0 < nbd0) { nbd0 = d0; nbi0 = j; }
            if (d1 < nbd1) { nbd1 = d1; nbi1 = 64 + j; }
            if (d2 < nbd2) { nbd2 = d2; nbi2 = 128 + j; }
            if (d3 < nbd3) { nbd3 = d3; nbi3 = 192 + j; }
        }

        float nbd = nbd0; int nbi = nbi0;
        if (nbd1 < nbd) { nbd = nbd1; nbi = nbi1; }
        if (nbd2 < nbd) { nbd = nbd2; nbi = nbi2; }
        if (nbd3 < nbd) { nbd = nbd3; nbi = nbi3; }
        bi = nbi;
        bv = sMeans[nbi];
    }

    // ---- Epilogue: store group 1 ----
    {
        float* p = base0 + (size_t)64 * M_MEANS;
        const int bvbits = __float_as_int(bv);
        #pragma unroll 4
        for (int j = 0; j < 64; ++j) {
            const int   sbi = __builtin_amdgcn_readlane(bi, j);
            const float sbv = __int_as_float(__builtin_amdgcn_readlane(bvbits, j));
            const int ee = sbi - cbase;
            f32x4 o;
            o.x = (ee == 0) ? sbv : 0.0f;
            o.y = (ee == 1) ? sbv : 0.0f;
            o.z = (ee == 2) ? sbv : 0.0f;
            o.w = (ee == 3) ? sbv : 0.0f;
            *reinterpret_cast<f32x4*>(p + (size_t)j * M_MEANS) = o;
        }
    }
}

extern "C" void kernel_launch(void* const* d_in, const int* in_sizes, int n_in,
                              void* d_out, int out_size, void* d_ws, size_t ws_size,
                              hipStream_t stream) {
    const float* target = (const float*)d_in[0];
    const float* means  = (const float*)d_in[1];
    float* out = (float*)d_out;
    const int N = in_sizes[0];  // 1,048,576

    // 2048 blocks x 256 threads = 8192 waves = full residency (32 waves/CU);
    // wave w owns rows [128w, 128w+128) — one linear 128-KiB write stream.
    dim3 grid(2048), block(256);
    hipLaunchKernelGGL(TemperatureModel_81767587381683_kernel, grid, block, 0, stream,
                       target, means, out, N);
}